// Round 18
// baseline (47.807 us; speedup 1.0000x reference)
//
#include <hip/hip_runtime.h>
#include <hip/hip_bf16.h>

// ShuffleNet fused block-MLP, MI355X (gfx950).  R18: LDS-resident weights.
// Model: time tracks total vector-memory bytes through L1/L2 (~21 TB/s eff).
// Fix: per-WG (one np) stage the np's FULL weight slice to LDS once (72 KB,
// 67 MB chip-wide) instead of per-wave L2 re-reads (570 MB). Hot loop's only
// global loads: 4 contiguous xT frags per s-step (L2/L3). pack_x rebuilt
// LDS-staged + coalesced both sides. Math = R11..R17 (passed, 9.77e-4):
// pi-permuted w2 pack -> GEMM2 A-frag is the lane's own GEMM1 outputs;
// pi(k) = 32*(k>>5) + 16*((k>>2)&1) + 4*((k>>3)&3) + (k&3).
// xT frag (rt,n,ks): lane l elem e = bf16(x[rt*16+(l&15)][n*64+ks*32+(l>>4)*8+e])
//   at xT[((rt*16+n)*2+ks)*512 + l*8 + e].

typedef __attribute__((ext_vector_type(8))) short  short8;   // 8 bf16 = 4 VGPR
typedef __attribute__((ext_vector_type(4))) short  short4v;
typedef __attribute__((ext_vector_type(4))) float  floatx4;

#define XP 1032   // pack_x LDS row pitch (516 dw = 4 mod 32 -> bank rotation)

__device__ __forceinline__ short f2bf(float f) {
  union { __hip_bfloat16 h; short s; } u;
  u.h = __float2bfloat16(f);
  return u.s;
}
__device__ __forceinline__ float bf2f(short s) {
  union { float f; unsigned u; } uu;
  uu.u = ((unsigned)(unsigned short)s) << 16;
  return uu.f;
}
__device__ __forceinline__ int pk16(float a, float b) {
  return (int)(unsigned short)f2bf(a) | ((int)(unsigned short)f2bf(b) << 16);
}

// gelu(v) ~= v * sigmoid(1.5957691*(v + 0.044715 v^3)), exp2-folded (abs<5e-4)
__device__ __forceinline__ float gelu_f(float v) {
  float m = v * v;
  float c = fmaf(-0.1029375f, m, -2.3020807f);
  float z = v * c;
  float e = __builtin_amdgcn_exp2f(z);
  return v * __builtin_amdgcn_rcpf(1.0f + e);
}

// ---- pack kernel: w1 frags | w2 frags (pi-permuted) | b1 frags (bf16) ----
__global__ void pack_k(const float* __restrict__ w1, const float* __restrict__ w2,
                       const float* __restrict__ b1, short* __restrict__ w1p,
                       short* __restrict__ w2p, short* __restrict__ b1p) {
  const int t = blockIdx.x * blockDim.x + threadIdx.x;  // 160*512 = 81920
  const int lane = t & 63;
  const int lhi = lane >> 4;
  if (t < 32768) {  // w1 frag (n,np,ks): lane l elem e = w1[n][np*16+(l&15)][ks*32+lhi*8+e]
    const int ks = (t >> 6) & 1, np = (t >> 7) & 15, n = (t >> 11) & 15;
    const float* src = w1 + ((size_t)(n * 256 + np * 16 + (lane & 15)) * 64 + ks * 32 + lhi * 8);
    short8 f;
#pragma unroll
    for (int e = 0; e < 8; ++e) f[e] = f2bf(src[e]);
    *(short8*)(w1p + (size_t)t * 8) = f;
  } else if (t < 65536) {  // w2 frag (np,s,ot), pi-permuted k
    const int t2 = t - 32768;
    const int ot = (t2 >> 6) & 3, s = (t2 >> 8) & 7, np = (t2 >> 11) & 15;
    const int op = ot * 16 + (lane & 15);
    short8 f;
#pragma unroll
    for (int e = 0; e < 8; ++e) {
      const int Kc = 32 * s + 16 * ((e >> 2) & 1) + 4 * lhi + (e & 3);
      const int n = Kc >> 4, ohi = Kc & 15;
      f[e] = f2bf(w2[(size_t)(np * 64 + op) * 256 + ohi * 16 + n]);
    }
    *(short8*)(w2p + (size_t)t2 * 8) = f;
  } else {  // b1 frag (n,np): lane l reg r = bf16(b1[(np*16+lhi*4+r)*16+n])
    const int t3 = t - 65536;  // 16384
    const int np = (t3 >> 6) & 15, n = (t3 >> 10) & 15;
    short4v b;
#pragma unroll
    for (int r = 0; r < 4; ++r) b[r] = f2bf(b1[(np * 16 + lhi * 4 + r) * 16 + n]);
    *(short4v*)(b1p + (size_t)((n * 16 + np) * 64 + lane) * 4) = b;
  }
}

// ---- pack_x: LDS-staged transpose, coalesced both sides. 512 WGs x 256. ----
__global__ __launch_bounds__(256, 4) void pack_x(
    const float* __restrict__ x, short* __restrict__ xT) {
  __shared__ __align__(16) short xs[16 * XP];
  const int tid = threadIdx.x;
  const int wv = tid >> 6, lane = tid & 63;
  const int l15 = lane & 15, lhi = lane >> 4;
  const int rt = blockIdx.x;

  // load: row j, thread covers 4 consecutive floats -> 4KB fully coalesced/row
#pragma unroll
  for (int j = 0; j < 16; ++j) {
    floatx4 v = __builtin_nontemporal_load(
        (const floatx4*)(x + (size_t)(rt * 16 + j) * 1024 + tid * 4));
    short4v s;
#pragma unroll
    for (int e = 0; e < 4; ++e) s[e] = f2bf(v[e]);
    *(short4v*)(&xs[j * XP + tid * 4]) = s;
  }
  __syncthreads();

  // write frags: wave wv -> frags f = wv*8+i (n = f>>1, ks = f&1); 1KB/instr
#pragma unroll
  for (int i = 0; i < 8; ++i) {
    const int f = wv * 8 + i, n = f >> 1, ks = f & 1;
    short8 fr = *(const short8*)(&xs[l15 * XP + n * 64 + ks * 32 + lhi * 8]);
    *(short8*)(xT + ((size_t)(rt * 16 + n) * 2 + ks) * 512 + lane * 8) = fr;
  }
}

// ---- fused: 1024 WGs x 512 thr; WG = (np = b&15, grp = b>>4); 72KB LDS ----
// wave wv streams rowtile rt = grp*8 + wv; all weights read from LDS.
__global__ __launch_bounds__(512, 4) void fused_k(
    const short* __restrict__ xT, const short* __restrict__ w1p,
    const short* __restrict__ w2p, const short* __restrict__ b1p,
    const float* __restrict__ b2, float* __restrict__ y) {
  __shared__ __align__(16) short lw1[16384];  // 32 KB: w1 np-slice (frag order)
  __shared__ __align__(16) short lw2[16384];  // 32 KB: w2 np-slice (contiguous)
  __shared__ __align__(16) short lb1[4096];   //  8 KB: b1 np-slice

  const int tid = threadIdx.x;
  const int wv = tid >> 6, lane = tid & 63;
  const int l15 = lane & 15, lhi = lane >> 4;
  const int np = blockIdx.x & 15;
  const int rt = (blockIdx.x >> 4) * 8 + wv;   // 0..511

  // ---- stage weights (coalesced; one pass) ----
#pragma unroll
  for (int i = 0; i < 4; ++i) {                // lw1: 2048 short8, chunk c=n*2+ks
    const int u = i * 512 + tid;
    const int c = u >> 6, e = u & 63;
    const size_t so = (((size_t)(c >> 1) * 16 + np) * 2 + (c & 1)) * 512 + e * 8;
    *(short8*)(&lw1[c * 512 + e * 8]) = *(const short8*)(w1p + so);
  }
  {
    const short* src = w2p + (size_t)np * 16384;   // contiguous np-slice
#pragma unroll
    for (int i = 0; i < 4; ++i) {
      const int off = (i * 512 + tid) * 8;
      *(short8*)(&lw2[off]) = *(const short8*)(src + off);
    }
  }
  {
    const int n = tid >> 5, e = tid & 31;          // lb1: 512 short8
    *(short8*)(&lb1[n * 256 + e * 8]) =
        *(const short8*)(b1p + (size_t)(n * 16 + np) * 256 + e * 8);
  }
  __syncthreads();   // the only barrier

  floatx4 c0 = {0.f,0.f,0.f,0.f}, c1 = {0.f,0.f,0.f,0.f};
  floatx4 c2 = {0.f,0.f,0.f,0.f}, c3 = {0.f,0.f,0.f,0.f};

#pragma unroll
  for (int s = 0; s < 8; ++s) {
    union { int i[4]; short8 v; } af;

#pragma unroll
    for (int half = 0; half < 2; ++half) {
      const int n = 2 * s + half;
      // only global loads in the hot loop: 2 contiguous xT frags
      short8 xf0 = *(const short8*)(xT + ((size_t)(rt * 16 + n) * 2 + 0) * 512 + lane * 8);
      short8 xf1 = *(const short8*)(xT + ((size_t)(rt * 16 + n) * 2 + 1) * 512 + lane * 8);
      short8 wf0 = *(const short8*)(&lw1[(n * 2 + 0) * 512 + lane * 8]);
      short8 wf1 = *(const short8*)(&lw1[(n * 2 + 1) * 512 + lane * 8]);
      short4v bv = *(const short4v*)(&lb1[n * 256 + lane * 4]);
      floatx4 acc = {0.f, 0.f, 0.f, 0.f};
      acc = __builtin_amdgcn_mfma_f32_16x16x32_bf16(wf0, xf0, acc, 0, 0, 0);
      acc = __builtin_amdgcn_mfma_f32_16x16x32_bf16(wf1, xf1, acc, 0, 0, 0);
      af.i[2 * half + 0] = pk16(gelu_f(acc[0] + bf2f(bv[0])), gelu_f(acc[1] + bf2f(bv[1])));
      af.i[2 * half + 1] = pk16(gelu_f(acc[2] + bf2f(bv[2])), gelu_f(acc[3] + bf2f(bv[3])));
    }

    // GEMM2 slice s: A-frag = lane's own registers (pi-fold); B from LDS
    short8 bf0  = *(const short8*)(&lw2[(s * 4 + 0) * 512 + lane * 8]);
    short8 bf1  = *(const short8*)(&lw2[(s * 4 + 1) * 512 + lane * 8]);
    short8 bf2v = *(const short8*)(&lw2[(s * 4 + 2) * 512 + lane * 8]);
    short8 bf3  = *(const short8*)(&lw2[(s * 4 + 3) * 512 + lane * 8]);
    c0 = __builtin_amdgcn_mfma_f32_16x16x32_bf16(af.v, bf0,  c0, 0, 0, 0);
    c1 = __builtin_amdgcn_mfma_f32_16x16x32_bf16(af.v, bf1,  c1, 0, 0, 0);
    c2 = __builtin_amdgcn_mfma_f32_16x16x32_bf16(af.v, bf2v, c2, 0, 0, 0);
    c3 = __builtin_amdgcn_mfma_f32_16x16x32_bf16(af.v, bf3,  c3, 0, 0, 0);
  }

  // ---- y store (NT): col = np*64 + ot*16 + l15, rows rt*16 + lhi*4 + r ----
  floatx4 cc[4] = {c0, c1, c2, c3};
#pragma unroll
  for (int ot = 0; ot < 4; ++ot) {
    const int col = np * 64 + ot * 16 + l15;
    const float bb = b2[col];
    float* py = y + (size_t)(rt * 16 + lhi * 4) * 1024 + col;
#pragma unroll
    for (int r = 0; r < 4; ++r)
      __builtin_nontemporal_store(cc[ot][r] + bb, py + (size_t)r * 1024);
  }
}

extern "C" void kernel_launch(void* const* d_in, const int* in_sizes, int n_in,
                              void* d_out, int out_size, void* d_ws, size_t ws_size,
                              hipStream_t stream) {
  const float* x  = (const float*)d_in[0];
  const float* w1 = (const float*)d_in[1];
  const float* b1 = (const float*)d_in[2];
  const float* w2 = (const float*)d_in[3];
  const float* b2 = (const float*)d_in[4];
  float* y = (float*)d_out;

  short* w1p = (short*)d_ws;               // 512 KB
  short* w2p = w1p + 16 * 256 * 64;        // 512 KB
  short* b1p = w2p + 16 * 256 * 64;        // 128 KB
  short* xT  = b1p + 16 * 16 * 64 * 4;     // 16 MB (bf16 fragment-order x)

  pack_k<<<160, 512, 0, stream>>>(w1, w2, b1, w1p, w2p, b1p);
  pack_x<<<512, 256, 0, stream>>>(x, xT);
  fused_k<<<1024, 512, 0, stream>>>(xT, w1p, w2p, b1p, b2, y);
}

// Round 19
// 47.185 us; speedup vs baseline: 1.0132x; 1.0132x over previous
//
#include <hip/hip_runtime.h>
#include <hip/hip_bf16.h>

// ShuffleNet fused block-MLP, MI355X (gfx950).  R19 = R18 (LDS-resident
// weights; first real improvement, -9.4us total) at FULL occupancy:
// WG = 1024 thr (16 waves) share one np's 72KB weight slice -> 2 WG/CU =
// 32 waves/CU (R18: 512thr -> 16 waves/CU). Streamed data (xT in, y out)
// stays global/NT; reused data (w1,w2,b1) read from LDS.
// Math = R11..R18 (passed, absmax 9.77e-4): pi-permuted w2 pack makes
// GEMM2's A-frag the lane's own GEMM1 outputs (register-local shuffle);
// pi(k) = 32*(k>>5) + 16*((k>>2)&1) + 4*((k>>3)&3) + (k&3).
// xT frag (rt,n,ks): lane l elem e = bf16(x[rt*16+(l&15)][n*64+ks*32+(l>>4)*8+e])
//   at xT[((rt*16+n)*2+ks)*512 + l*8 + e].

typedef __attribute__((ext_vector_type(8))) short  short8;   // 8 bf16 = 4 VGPR
typedef __attribute__((ext_vector_type(4))) short  short4v;
typedef __attribute__((ext_vector_type(4))) float  floatx4;

#define XP 1032   // pack_x LDS row pitch (516 dw = 4 mod 32 -> bank rotation)

__device__ __forceinline__ short f2bf(float f) {
  union { __hip_bfloat16 h; short s; } u;
  u.h = __float2bfloat16(f);
  return u.s;
}
__device__ __forceinline__ float bf2f(short s) {
  union { float f; unsigned u; } uu;
  uu.u = ((unsigned)(unsigned short)s) << 16;
  return uu.f;
}
__device__ __forceinline__ int pk16(float a, float b) {
  return (int)(unsigned short)f2bf(a) | ((int)(unsigned short)f2bf(b) << 16);
}

// gelu(v) ~= v * sigmoid(1.5957691*(v + 0.044715 v^3)), exp2-folded (abs<5e-4)
__device__ __forceinline__ float gelu_f(float v) {
  float m = v * v;
  float c = fmaf(-0.1029375f, m, -2.3020807f);
  float z = v * c;
  float e = __builtin_amdgcn_exp2f(z);
  return v * __builtin_amdgcn_rcpf(1.0f + e);
}

// ---- pack kernel: w1 frags | w2 frags (pi-permuted) | b1 frags (bf16) ----
__global__ void pack_k(const float* __restrict__ w1, const float* __restrict__ w2,
                       const float* __restrict__ b1, short* __restrict__ w1p,
                       short* __restrict__ w2p, short* __restrict__ b1p) {
  const int t = blockIdx.x * blockDim.x + threadIdx.x;  // 160*512 = 81920
  const int lane = t & 63;
  const int lhi = lane >> 4;
  if (t < 32768) {  // w1 frag (n,np,ks): lane l elem e = w1[n][np*16+(l&15)][ks*32+lhi*8+e]
    const int ks = (t >> 6) & 1, np = (t >> 7) & 15, n = (t >> 11) & 15;
    const float* src = w1 + ((size_t)(n * 256 + np * 16 + (lane & 15)) * 64 + ks * 32 + lhi * 8);
    short8 f;
#pragma unroll
    for (int e = 0; e < 8; ++e) f[e] = f2bf(src[e]);
    *(short8*)(w1p + (size_t)t * 8) = f;
  } else if (t < 65536) {  // w2 frag (np,s,ot), pi-permuted k
    const int t2 = t - 32768;
    const int ot = (t2 >> 6) & 3, s = (t2 >> 8) & 7, np = (t2 >> 11) & 15;
    const int op = ot * 16 + (lane & 15);
    short8 f;
#pragma unroll
    for (int e = 0; e < 8; ++e) {
      const int Kc = 32 * s + 16 * ((e >> 2) & 1) + 4 * lhi + (e & 3);
      const int n = Kc >> 4, ohi = Kc & 15;
      f[e] = f2bf(w2[(size_t)(np * 64 + op) * 256 + ohi * 16 + n]);
    }
    *(short8*)(w2p + (size_t)t2 * 8) = f;
  } else {  // b1 frag (n,np): lane l reg r = bf16(b1[(np*16+lhi*4+r)*16+n])
    const int t3 = t - 65536;  // 16384
    const int np = (t3 >> 6) & 15, n = (t3 >> 10) & 15;
    short4v b;
#pragma unroll
    for (int r = 0; r < 4; ++r) b[r] = f2bf(b1[(np * 16 + lhi * 4 + r) * 16 + n]);
    *(short4v*)(b1p + (size_t)((n * 16 + np) * 64 + lane) * 4) = b;
  }
}

// ---- pack_x: LDS-staged transpose, coalesced both sides. 512 WGs x 256. ----
__global__ __launch_bounds__(256, 4) void pack_x(
    const float* __restrict__ x, short* __restrict__ xT) {
  __shared__ __align__(16) short xs[16 * XP];
  const int tid = threadIdx.x;
  const int wv = tid >> 6, lane = tid & 63;
  const int l15 = lane & 15, lhi = lane >> 4;
  const int rt = blockIdx.x;

#pragma unroll
  for (int j = 0; j < 16; ++j) {
    floatx4 v = __builtin_nontemporal_load(
        (const floatx4*)(x + (size_t)(rt * 16 + j) * 1024 + tid * 4));
    short4v s;
#pragma unroll
    for (int e = 0; e < 4; ++e) s[e] = f2bf(v[e]);
    *(short4v*)(&xs[j * XP + tid * 4]) = s;
  }
  __syncthreads();

#pragma unroll
  for (int i = 0; i < 8; ++i) {
    const int f = wv * 8 + i, n = f >> 1, ks = f & 1;
    short8 fr = *(const short8*)(&xs[l15 * XP + n * 64 + ks * 32 + lhi * 8]);
    *(short8*)(xT + ((size_t)(rt * 16 + n) * 2 + ks) * 512 + lane * 8) = fr;
  }
}

// ---- fused: 512 WGs x 1024 thr (16 waves); WG = (np = b&15, rtg = b>>4) ----
// wave wv streams rowtile rt = rtg*16 + wv; all weights read from LDS.
__global__ __launch_bounds__(1024, 2) void fused_k(
    const short* __restrict__ xT, const short* __restrict__ w1p,
    const short* __restrict__ w2p, const short* __restrict__ b1p,
    const float* __restrict__ b2, float* __restrict__ y) {
  __shared__ __align__(16) short lw1[16384];  // 32 KB: w1 np-slice (frag order)
  __shared__ __align__(16) short lw2[16384];  // 32 KB: w2 np-slice
  __shared__ __align__(16) short lb1[4096];   //  8 KB: b1 np-slice

  const int tid = threadIdx.x;
  const int wv = tid >> 6, lane = tid & 63;
  const int l15 = lane & 15, lhi = lane >> 4;
  const int np = blockIdx.x & 15;
  const int rt = (blockIdx.x >> 4) * 16 + wv;   // 0..511

  // ---- stage weights (coalesced; one pass; 1024 threads) ----
#pragma unroll
  for (int i = 0; i < 2; ++i) {                // lw1: 2048 short8
    const int u = i * 1024 + tid;
    const int c = u >> 6, e = u & 63;          // chunk c = n*2+ks
    const size_t so = (((size_t)(c >> 1) * 16 + np) * 2 + (c & 1)) * 512 + e * 8;
    *(short8*)(&lw1[c * 512 + e * 8]) = *(const short8*)(w1p + so);
  }
  {
    const short* src = w2p + (size_t)np * 16384;   // contiguous np-slice
#pragma unroll
    for (int i = 0; i < 2; ++i) {
      const int off = (i * 1024 + tid) * 8;
      *(short8*)(&lw2[off]) = *(const short8*)(src + off);
    }
  }
  if (tid < 512) {                              // lb1: 512 short8
    const int n = tid >> 5, e = tid & 31;
    *(short8*)(&lb1[n * 256 + e * 8]) =
        *(const short8*)(b1p + (size_t)(n * 16 + np) * 256 + e * 8);
  }
  __syncthreads();   // the only barrier

  floatx4 c0 = {0.f,0.f,0.f,0.f}, c1 = {0.f,0.f,0.f,0.f};
  floatx4 c2 = {0.f,0.f,0.f,0.f}, c3 = {0.f,0.f,0.f,0.f};

#pragma unroll
  for (int s = 0; s < 8; ++s) {
    union { int i[4]; short8 v; } af;

#pragma unroll
    for (int half = 0; half < 2; ++half) {
      const int n = 2 * s + half;
      // only global loads in the hot loop: 2 contiguous xT frags
      short8 xf0 = *(const short8*)(xT + ((size_t)(rt * 16 + n) * 2 + 0) * 512 + lane * 8);
      short8 xf1 = *(const short8*)(xT + ((size_t)(rt * 16 + n) * 2 + 1) * 512 + lane * 8);
      short8 wf0 = *(const short8*)(&lw1[(n * 2 + 0) * 512 + lane * 8]);
      short8 wf1 = *(const short8*)(&lw1[(n * 2 + 1) * 512 + lane * 8]);
      short4v bv = *(const short4v*)(&lb1[n * 256 + lane * 4]);
      floatx4 acc = {0.f, 0.f, 0.f, 0.f};
      acc = __builtin_amdgcn_mfma_f32_16x16x32_bf16(wf0, xf0, acc, 0, 0, 0);
      acc = __builtin_amdgcn_mfma_f32_16x16x32_bf16(wf1, xf1, acc, 0, 0, 0);
      af.i[2 * half + 0] = pk16(gelu_f(acc[0] + bf2f(bv[0])), gelu_f(acc[1] + bf2f(bv[1])));
      af.i[2 * half + 1] = pk16(gelu_f(acc[2] + bf2f(bv[2])), gelu_f(acc[3] + bf2f(bv[3])));
    }

    // GEMM2 slice s: A-frag = lane's own registers (pi-fold); B from LDS
    short8 bf0  = *(const short8*)(&lw2[(s * 4 + 0) * 512 + lane * 8]);
    short8 bf1  = *(const short8*)(&lw2[(s * 4 + 1) * 512 + lane * 8]);
    short8 bf2v = *(const short8*)(&lw2[(s * 4 + 2) * 512 + lane * 8]);
    short8 bf3  = *(const short8*)(&lw2[(s * 4 + 3) * 512 + lane * 8]);
    c0 = __builtin_amdgcn_mfma_f32_16x16x32_bf16(af.v, bf0,  c0, 0, 0, 0);
    c1 = __builtin_amdgcn_mfma_f32_16x16x32_bf16(af.v, bf1,  c1, 0, 0, 0);
    c2 = __builtin_amdgcn_mfma_f32_16x16x32_bf16(af.v, bf2v, c2, 0, 0, 0);
    c3 = __builtin_amdgcn_mfma_f32_16x16x32_bf16(af.v, bf3,  c3, 0, 0, 0);
  }

  // ---- y store (NT): col = np*64 + ot*16 + l15, rows rt*16 + lhi*4 + r ----
  floatx4 cc[4] = {c0, c1, c2, c3};
#pragma unroll
  for (int ot = 0; ot < 4; ++ot) {
    const int col = np * 64 + ot * 16 + l15;
    const float bb = b2[col];
    float* py = y + (size_t)(rt * 16 + lhi * 4) * 1024 + col;
#pragma unroll
    for (int r = 0; r < 4; ++r)
      __builtin_nontemporal_store(cc[ot][r] + bb, py + (size_t)r * 1024);
  }
}

extern "C" void kernel_launch(void* const* d_in, const int* in_sizes, int n_in,
                              void* d_out, int out_size, void* d_ws, size_t ws_size,
                              hipStream_t stream) {
  const float* x  = (const float*)d_in[0];
  const float* w1 = (const float*)d_in[1];
  const float* b1 = (const float*)d_in[2];
  const float* w2 = (const float*)d_in[3];
  const float* b2 = (const float*)d_in[4];
  float* y = (float*)d_out;

  short* w1p = (short*)d_ws;               // 512 KB
  short* w2p = w1p + 16 * 256 * 64;        // 512 KB
  short* b1p = w2p + 16 * 256 * 64;        // 128 KB
  short* xT  = b1p + 16 * 16 * 64 * 4;     // 16 MB (bf16 fragment-order x)

  pack_k<<<160, 512, 0, stream>>>(w1, w2, b1, w1p, w2p, b1p);
  pack_x<<<512, 256, 0, stream>>>(x, xT);
  fused_k<<<512, 1024, 0, stream>>>(xT, w1p, w2p, b1p, b2, y);
}

// Round 20
// 42.197 us; speedup vs baseline: 1.1330x; 1.1182x over previous
//
#include <hip/hip_runtime.h>
#include <hip/hip_bf16.h>

// ShuffleNet fused block-MLP, MI355X (gfx950).  R20 = R19 + XCD-aligned
// producer->consumer decode + 2-deep xT prefetch.
// Model (fits R4..R19): wall = per-wave serial load chain; extra waves never
// shorten it. R19's xT loads were cross-XCD L3 trips (~700cy each on the
// chain) because pack_x wrote rt r on XCD r&7 but fused read rts 16g..16g+15
// from XCD b&7. Fix: np = b>>6, g = b&63, rt = wv*64 + g -> rt = g (mod 8) ->
// reader XCD == writer XCD == rt&7: xT loads become same-XCD L2 hits; plus
// issue-early prefetch of the next step's 4 xT frags (named regs).
// Weights stay LDS-resident (R18's win). Math = R11..R19 (passed, 9.77e-4):
// pi-permuted w2 pack -> GEMM2 A-frag is the lane's own GEMM1 outputs;
// pi(k) = 32*(k>>5) + 16*((k>>2)&1) + 4*((k>>3)&3) + (k&3).
// xT frag (rt,n,ks): lane l elem e = bf16(x[rt*16+(l&15)][n*64+ks*32+(l>>4)*8+e])
//   at xT[((rt*16+n)*2+ks)*512 + l*8 + e].

typedef __attribute__((ext_vector_type(8))) short  short8;   // 8 bf16 = 4 VGPR
typedef __attribute__((ext_vector_type(4))) short  short4v;
typedef __attribute__((ext_vector_type(4))) float  floatx4;

#define XP 1032   // pack_x LDS row pitch (516 dw = 4 mod 32 -> bank rotation)

__device__ __forceinline__ short f2bf(float f) {
  union { __hip_bfloat16 h; short s; } u;
  u.h = __float2bfloat16(f);
  return u.s;
}
__device__ __forceinline__ float bf2f(short s) {
  union { float f; unsigned u; } uu;
  uu.u = ((unsigned)(unsigned short)s) << 16;
  return uu.f;
}
__device__ __forceinline__ int pk16(float a, float b) {
  return (int)(unsigned short)f2bf(a) | ((int)(unsigned short)f2bf(b) << 16);
}

// gelu(v) ~= v * sigmoid(1.5957691*(v + 0.044715 v^3)), exp2-folded (abs<5e-4)
__device__ __forceinline__ float gelu_f(float v) {
  float m = v * v;
  float c = fmaf(-0.1029375f, m, -2.3020807f);
  float z = v * c;
  float e = __builtin_amdgcn_exp2f(z);
  return v * __builtin_amdgcn_rcpf(1.0f + e);
}

// ---- pack kernel: w1 frags | w2 frags (pi-permuted) | b1 frags (bf16) ----
__global__ void pack_k(const float* __restrict__ w1, const float* __restrict__ w2,
                       const float* __restrict__ b1, short* __restrict__ w1p,
                       short* __restrict__ w2p, short* __restrict__ b1p) {
  const int t = blockIdx.x * blockDim.x + threadIdx.x;  // 160*512 = 81920
  const int lane = t & 63;
  const int lhi = lane >> 4;
  if (t < 32768) {  // w1 frag (n,np,ks): lane l elem e = w1[n][np*16+(l&15)][ks*32+lhi*8+e]
    const int ks = (t >> 6) & 1, np = (t >> 7) & 15, n = (t >> 11) & 15;
    const float* src = w1 + ((size_t)(n * 256 + np * 16 + (lane & 15)) * 64 + ks * 32 + lhi * 8);
    short8 f;
#pragma unroll
    for (int e = 0; e < 8; ++e) f[e] = f2bf(src[e]);
    *(short8*)(w1p + (size_t)t * 8) = f;
  } else if (t < 65536) {  // w2 frag (np,s,ot), pi-permuted k
    const int t2 = t - 32768;
    const int ot = (t2 >> 6) & 3, s = (t2 >> 8) & 7, np = (t2 >> 11) & 15;
    const int op = ot * 16 + (lane & 15);
    short8 f;
#pragma unroll
    for (int e = 0; e < 8; ++e) {
      const int Kc = 32 * s + 16 * ((e >> 2) & 1) + 4 * lhi + (e & 3);
      const int n = Kc >> 4, ohi = Kc & 15;
      f[e] = f2bf(w2[(size_t)(np * 64 + op) * 256 + ohi * 16 + n]);
    }
    *(short8*)(w2p + (size_t)t2 * 8) = f;
  } else {  // b1 frag (n,np): lane l reg r = bf16(b1[(np*16+lhi*4+r)*16+n])
    const int t3 = t - 65536;  // 16384
    const int np = (t3 >> 6) & 15, n = (t3 >> 10) & 15;
    short4v b;
#pragma unroll
    for (int r = 0; r < 4; ++r) b[r] = f2bf(b1[(np * 16 + lhi * 4 + r) * 16 + n]);
    *(short4v*)(b1p + (size_t)((n * 16 + np) * 64 + lane) * 4) = b;
  }
}

// ---- pack_x: LDS-staged transpose; block g -> rt g (XCD g&7). 512 x 256. ----
__global__ __launch_bounds__(256, 4) void pack_x(
    const float* __restrict__ x, short* __restrict__ xT) {
  __shared__ __align__(16) short xs[16 * XP];
  const int tid = threadIdx.x;
  const int wv = tid >> 6, lane = tid & 63;
  const int l15 = lane & 15, lhi = lane >> 4;
  const int rt = blockIdx.x;

#pragma unroll
  for (int j = 0; j < 16; ++j) {
    floatx4 v = __builtin_nontemporal_load(
        (const floatx4*)(x + (size_t)(rt * 16 + j) * 1024 + tid * 4));
    short4v s;
#pragma unroll
    for (int e = 0; e < 4; ++e) s[e] = f2bf(v[e]);
    *(short4v*)(&xs[j * XP + tid * 4]) = s;
  }
  __syncthreads();

#pragma unroll
  for (int i = 0; i < 8; ++i) {
    const int f = wv * 8 + i, n = f >> 1, ks = f & 1;
    short8 fr = *(const short8*)(&xs[l15 * XP + n * 64 + ks * 32 + lhi * 8]);
    *(short8*)(xT + ((size_t)(rt * 16 + n) * 2 + ks) * 512 + lane * 8) = fr;
  }
}

// x-frag load macro (named regs; the only global loads in the hot loop)
#define XLOAD(P0, P1, P2, P3, ss) {                                            \
  const int n0_ = 2 * (ss), n1_ = n0_ + 1;                                     \
  P0 = *(const short8*)(xT + ((size_t)(rt * 16 + n0_) * 2 + 0) * 512 + lane * 8); \
  P1 = *(const short8*)(xT + ((size_t)(rt * 16 + n0_) * 2 + 1) * 512 + lane * 8); \
  P2 = *(const short8*)(xT + ((size_t)(rt * 16 + n1_) * 2 + 0) * 512 + lane * 8); \
  P3 = *(const short8*)(xT + ((size_t)(rt * 16 + n1_) * 2 + 1) * 512 + lane * 8); \
}

// ---- fused: 1024 WGs x 512 thr; np = b>>6, g = b&63; wave wv: rt = wv*64+g ----
__global__ __launch_bounds__(512, 4) void fused_k(
    const short* __restrict__ xT, const short* __restrict__ w1p,
    const short* __restrict__ w2p, const short* __restrict__ b1p,
    const float* __restrict__ b2, float* __restrict__ y) {
  __shared__ __align__(16) short lw1[16384];  // 32 KB: w1 np-slice (frag order)
  __shared__ __align__(16) short lw2[16384];  // 32 KB: w2 np-slice
  __shared__ __align__(16) short lb1[4096];   //  8 KB: b1 np-slice

  const int tid = threadIdx.x;
  const int wv = tid >> 6, lane = tid & 63;
  const int l15 = lane & 15, lhi = lane >> 4;
  const int np = blockIdx.x >> 6;              // 0..15
  const int g  = blockIdx.x & 63;              // XCD = g&7
  const int rt = wv * 64 + g;                  // rt = g (mod 8) -> same XCD as pack_x writer

  // ---- stage weights (coalesced; one pass; 512 threads) ----
#pragma unroll
  for (int i = 0; i < 4; ++i) {                // lw1: 2048 short8, chunk c = n*2+ks
    const int u = i * 512 + tid;
    const int c = u >> 6, e = u & 63;
    const size_t so = (((size_t)(c >> 1) * 16 + np) * 2 + (c & 1)) * 512 + e * 8;
    *(short8*)(&lw1[c * 512 + e * 8]) = *(const short8*)(w1p + so);
  }
  {
    const short* src = w2p + (size_t)np * 16384;   // contiguous np-slice
#pragma unroll
    for (int i = 0; i < 4; ++i) {
      const int off = (i * 512 + tid) * 8;
      *(short8*)(&lw2[off]) = *(const short8*)(src + off);
    }
  }
  {
    const int n = tid >> 5, e = tid & 31;          // lb1: 512 short8
    *(short8*)(&lb1[n * 256 + e * 8]) =
        *(const short8*)(b1p + (size_t)(n * 16 + np) * 256 + e * 8);
  }
  __syncthreads();   // the only barrier

  floatx4 c0 = {0.f,0.f,0.f,0.f}, c1 = {0.f,0.f,0.f,0.f};
  floatx4 c2 = {0.f,0.f,0.f,0.f}, c3 = {0.f,0.f,0.f,0.f};

  short8 xA0, xA1, xA2, xA3, xB0, xB1, xB2, xB3;
  XLOAD(xA0, xA1, xA2, xA3, 0)

#pragma unroll
  for (int s = 0; s < 8; ++s) {
    // prefetch next step's x frags (issue-early; independent of current compute)
    if (s < 7) {
      if (s & 1) { XLOAD(xA0, xA1, xA2, xA3, s + 1) }
      else       { XLOAD(xB0, xB1, xB2, xB3, s + 1) }
    }
    const short8 xf00 = (s & 1) ? xB0 : xA0;   // n = 2s,   ks = 0
    const short8 xf01 = (s & 1) ? xB1 : xA1;   // n = 2s,   ks = 1
    const short8 xf10 = (s & 1) ? xB2 : xA2;   // n = 2s+1, ks = 0
    const short8 xf11 = (s & 1) ? xB3 : xA3;   // n = 2s+1, ks = 1

    union { int i[4]; short8 v; } af;
    {
      const int n = 2 * s;
      short8 wf0 = *(const short8*)(&lw1[(n * 2 + 0) * 512 + lane * 8]);
      short8 wf1 = *(const short8*)(&lw1[(n * 2 + 1) * 512 + lane * 8]);
      short4v bv = *(const short4v*)(&lb1[n * 256 + lane * 4]);
      floatx4 acc = {0.f, 0.f, 0.f, 0.f};
      acc = __builtin_amdgcn_mfma_f32_16x16x32_bf16(wf0, xf00, acc, 0, 0, 0);
      acc = __builtin_amdgcn_mfma_f32_16x16x32_bf16(wf1, xf01, acc, 0, 0, 0);
      af.i[0] = pk16(gelu_f(acc[0] + bf2f(bv[0])), gelu_f(acc[1] + bf2f(bv[1])));
      af.i[1] = pk16(gelu_f(acc[2] + bf2f(bv[2])), gelu_f(acc[3] + bf2f(bv[3])));
    }
    {
      const int n = 2 * s + 1;
      short8 wf0 = *(const short8*)(&lw1[(n * 2 + 0) * 512 + lane * 8]);
      short8 wf1 = *(const short8*)(&lw1[(n * 2 + 1) * 512 + lane * 8]);
      short4v bv = *(const short4v*)(&lb1[n * 256 + lane * 4]);
      floatx4 acc = {0.f, 0.f, 0.f, 0.f};
      acc = __builtin_amdgcn_mfma_f32_16x16x32_bf16(wf0, xf10, acc, 0, 0, 0);
      acc = __builtin_amdgcn_mfma_f32_16x16x32_bf16(wf1, xf11, acc, 0, 0, 0);
      af.i[2] = pk16(gelu_f(acc[0] + bf2f(bv[0])), gelu_f(acc[1] + bf2f(bv[1])));
      af.i[3] = pk16(gelu_f(acc[2] + bf2f(bv[2])), gelu_f(acc[3] + bf2f(bv[3])));
    }

    // GEMM2 slice s: A-frag = lane's own registers (pi-fold); B from LDS
    short8 bf0  = *(const short8*)(&lw2[(s * 4 + 0) * 512 + lane * 8]);
    short8 bf1  = *(const short8*)(&lw2[(s * 4 + 1) * 512 + lane * 8]);
    short8 bf2v = *(const short8*)(&lw2[(s * 4 + 2) * 512 + lane * 8]);
    short8 bf3  = *(const short8*)(&lw2[(s * 4 + 3) * 512 + lane * 8]);
    c0 = __builtin_amdgcn_mfma_f32_16x16x32_bf16(af.v, bf0,  c0, 0, 0, 0);
    c1 = __builtin_amdgcn_mfma_f32_16x16x32_bf16(af.v, bf1,  c1, 0, 0, 0);
    c2 = __builtin_amdgcn_mfma_f32_16x16x32_bf16(af.v, bf2v, c2, 0, 0, 0);
    c3 = __builtin_amdgcn_mfma_f32_16x16x32_bf16(af.v, bf3,  c3, 0, 0, 0);
  }

  // ---- y store (NT): col = np*64 + ot*16 + l15, rows rt*16 + lhi*4 + r ----
  floatx4 cc[4] = {c0, c1, c2, c3};
#pragma unroll
  for (int ot = 0; ot < 4; ++ot) {
    const int col = np * 64 + ot * 16 + l15;
    const float bb = b2[col];
    float* py = y + (size_t)(rt * 16 + lhi * 4) * 1024 + col;
#pragma unroll
    for (int r = 0; r < 4; ++r)
      __builtin_nontemporal_store(cc[ot][r] + bb, py + (size_t)r * 1024);
  }
}

extern "C" void kernel_launch(void* const* d_in, const int* in_sizes, int n_in,
                              void* d_out, int out_size, void* d_ws, size_t ws_size,
                              hipStream_t stream) {
  const float* x  = (const float*)d_in[0];
  const float* w1 = (const float*)d_in[1];
  const float* b1 = (const float*)d_in[2];
  const float* w2 = (const float*)d_in[3];
  const float* b2 = (const float*)d_in[4];
  float* y = (float*)d_out;

  short* w1p = (short*)d_ws;               // 512 KB
  short* w2p = w1p + 16 * 256 * 64;        // 512 KB
  short* b1p = w2p + 16 * 256 * 64;        // 128 KB
  short* xT  = b1p + 16 * 16 * 64 * 4;     // 16 MB (bf16 fragment-order x)

  pack_k<<<160, 512, 0, stream>>>(w1, w2, b1, w1p, w2p, b1p);
  pack_x<<<512, 256, 0, stream>>>(x, xT);
  fused_k<<<1024, 512, 0, stream>>>(xT, w1p, w2p, b1p, b2, y);
}